// Round 1
// baseline (717.456 us; speedup 1.0000x reference)
//
#include <hip/hip_runtime.h>
#include <hip/hip_bf16.h>

typedef __attribute__((ext_vector_type(8))) short short8;
typedef __attribute__((ext_vector_type(4))) float f32x4;
typedef unsigned short ushort_t;

#define NTOK 262144   // B*D*H*W = 2*32*64*64

__device__ __forceinline__ ushort_t f2bf(float f){
  unsigned int x = __float_as_uint(f);
  unsigned int r = (x + 0x7fffu + ((x >> 16) & 1u)) >> 16;
  return (ushort_t)r;
}
__device__ __forceinline__ float bf2f(ushort_t u){
  union { unsigned int i; float f; } v; v.i = ((unsigned int)u) << 16; return v.f;
}
__device__ __forceinline__ float gelu_exact(float x){
  return 0.5f * x * (1.0f + erff(x * 0.70710678118654752440f));
}

// ---------------- weight prep: fp32 -> bf16, transposed to Bt[col][k] ----------------
__global__ __launch_bounds__(256) void prep_kernel(
    const float* __restrict__ wq, const float* __restrict__ wk, const float* __restrict__ wv,
    const float* __restrict__ wo, const float* __restrict__ w1, const float* __restrict__ w2,
    const float* __restrict__ bq, const float* __restrict__ bk, const float* __restrict__ bv,
    ushort_t* __restrict__ Wqkv, ushort_t* __restrict__ Wo,
    ushort_t* __restrict__ W1, ushort_t* __restrict__ W2, float* __restrict__ biasq)
{
  int i = blockIdx.x * 256 + threadIdx.x;
  if (i < 27648) {                       // Wqkv_t[j][c], j = s*96 + h*24 + d
    int j = i / 96, c = i % 96;
    int s = j / 96, rem = j % 96;
    const float* src = (s == 0) ? wq : (s == 1) ? wk : wv;
    Wqkv[j * 96 + c] = f2bf(src[c * 96 + rem]);
  } else if (i < 36864) {                // Wo_t[c][hd] = wo[hd][c]
    int ii = i - 27648;
    int c = ii / 96, hd = ii % 96;
    Wo[ii] = f2bf(wo[hd * 96 + c]);
  } else if (i < 73728) {                // W1_t[j][c] = w1[c][j]
    int ii = i - 36864;
    int j = ii / 96, c = ii % 96;
    W1[ii] = f2bf(w1[c * 384 + j]);
  } else if (i < 110592) {               // W2_t[c][j] = w2[j][c]
    int ii = i - 73728;
    int c = ii / 384, j = ii % 384;
    W2[ii] = f2bf(w2[j * 96 + c]);
  } else if (i < 110880) {               // combined qkv bias (fp32)
    int j = i - 110592;
    int s = j / 96, rem = j % 96;
    const float* src = (s == 0) ? bq : (s == 1) ? bk : bv;
    biasq[j] = src[rem];
  }
}

// ---------------- LayerNorm: one wave per token (96 channels) ----------------
__global__ __launch_bounds__(256) void ln_kernel(const float* __restrict__ x,
    const float* __restrict__ g, const float* __restrict__ b, ushort_t* __restrict__ out)
{
  int wid = (blockIdx.x * 256 + threadIdx.x) >> 6;   // token id
  int lane = threadIdx.x & 63;
  const float* xp = x + (size_t)wid * 96;
  float a0 = xp[lane];
  float a1 = (lane < 32) ? xp[64 + lane] : 0.0f;
  float s = a0 + a1, sq = a0 * a0 + a1 * a1;
  #pragma unroll
  for (int off = 32; off > 0; off >>= 1) {
    s  += __shfl_xor(s, off);
    sq += __shfl_xor(sq, off);
  }
  float mean = s * (1.0f / 96.0f);
  float var  = sq * (1.0f / 96.0f) - mean * mean;
  float rstd = rsqrtf(var + 1e-5f);
  ushort_t* op = out + (size_t)wid * 96;
  op[lane] = f2bf((a0 - mean) * rstd * g[lane] + b[lane]);
  if (lane < 32)
    op[64 + lane] = f2bf((a1 - mean) * rstd * g[64 + lane] + b[64 + lane]);
}

// ---------------- MFMA GEMM: A[M,K]bf16 @ Bt[NOUT,K]bf16 -> out, wave = 16 rows x 96 cols
// EPI: 0 = +bias -> bf16 ; 1 = +bias +res(fp32,[M,96]) -> fp32 ; 2 = +bias, gelu -> bf16
template<int K, int NTN, int EPI>
__global__ __launch_bounds__(256) void gemm_kernel(const ushort_t* __restrict__ A,
    const ushort_t* __restrict__ Bt, const float* __restrict__ bias,
    const float* __restrict__ res, void* __restrict__ outv)
{
  constexpr int NOUT = NTN * 96;
  int gid  = blockIdx.x * 4 + (threadIdx.x >> 6);
  int lane = threadIdx.x & 63;
  int tile_n = gid % NTN;
  int tile_m = gid / NTN;

  int rA = tile_m * 16 + (lane & 15);
  const ushort_t* Ap = A + (size_t)rA * K + ((lane >> 4) * 8);
  int colB0 = tile_n * 96 + (lane & 15);
  const ushort_t* Bp = Bt + (size_t)colB0 * K + ((lane >> 4) * 8);

  f32x4 acc[6];
  #pragma unroll
  for (int j = 0; j < 6; j++) acc[j] = (f32x4){0.f, 0.f, 0.f, 0.f};

  #pragma unroll
  for (int k0 = 0; k0 < K; k0 += 32) {
    short8 a = *reinterpret_cast<const short8*>(Ap + k0);
    #pragma unroll
    for (int j = 0; j < 6; j++) {
      short8 bfr = *reinterpret_cast<const short8*>(Bp + (size_t)j * 16 * K + k0);
      acc[j] = __builtin_amdgcn_mfma_f32_16x16x32_bf16(a, bfr, acc[j], 0, 0, 0);
    }
  }

  int r0 = tile_m * 16 + ((lane >> 4) * 4);
  int c0 = tile_n * 96 + (lane & 15);
  #pragma unroll
  for (int j = 0; j < 6; j++) {
    int col = c0 + j * 16;
    float bs = bias[col];
    #pragma unroll
    for (int r = 0; r < 4; r++) {
      size_t row = (size_t)(r0 + r);
      float v = acc[j][r] + bs;
      if constexpr (EPI == 2) v = gelu_exact(v);
      if constexpr (EPI == 1) {
        v += res[row * 96 + col];
        reinterpret_cast<float*>(outv)[row * NOUT + col] = v;
      } else {
        reinterpret_cast<ushort_t*>(outv)[row * NOUT + col] = f2bf(v);
      }
    }
  }
}

// ---------------- window attention: one wave per (window, head) ----------------
__global__ __launch_bounds__(64) void attn_kernel(const ushort_t* __restrict__ qkv,
                                                  ushort_t* __restrict__ o)
{
  __shared__ float Kf[64][25];
  __shared__ float Vf[64][25];
  int n = blockIdx.x >> 2;     // window id
  int h = blockIdx.x & 3;      // head
  int lane = threadIdx.x;

  // token for (window n, slot lane)
  int wq_ = n & 15, hq = (n >> 4) & 15, rest = n >> 8;
  int dq = rest & 7, b = rest >> 3;
  int dr = lane >> 4, hr = (lane >> 2) & 3, wr = lane & 3;
  size_t t = (((size_t)((b * 32 + dq * 4 + dr) * 64 + (hq * 4 + hr))) * 64 + (wq_ * 4 + wr));

  const ushort_t* base = qkv + t * 288 + h * 24;
  const float scale = 0.20412414523193150818f;   // 1/sqrt(24)
  float q[24];
  #pragma unroll
  for (int d = 0; d < 24; d++) q[d] = bf2f(base[d]) * scale;
  #pragma unroll
  for (int d = 0; d < 24; d++) Kf[lane][d] = bf2f(base[96 + d]);
  #pragma unroll
  for (int d = 0; d < 24; d++) Vf[lane][d] = bf2f(base[192 + d]);
  __syncthreads();

  float sc[64];
  float mx = -1e30f;
  #pragma unroll
  for (int m = 0; m < 64; m++) {
    float s = 0.f;
    #pragma unroll
    for (int d = 0; d < 24; d++) s += q[d] * Kf[m][d];
    sc[m] = s;
    mx = fmaxf(mx, s);
  }
  float sum = 0.f;
  float oa[24];
  #pragma unroll
  for (int d = 0; d < 24; d++) oa[d] = 0.f;
  #pragma unroll
  for (int m = 0; m < 64; m++) {
    float p = __expf(sc[m] - mx);
    sum += p;
    #pragma unroll
    for (int d = 0; d < 24; d++) oa[d] += p * Vf[m][d];
  }
  float inv = 1.0f / sum;
  ushort_t* op = o + t * 96 + h * 24;
  #pragma unroll
  for (int d = 0; d < 24; d++) op[d] = f2bf(oa[d] * inv);
}

// ---------------- launch ----------------
extern "C" void kernel_launch(void* const* d_in, const int* in_sizes, int n_in,
                              void* d_out, int out_size, void* d_ws, size_t ws_size,
                              hipStream_t stream)
{
  (void)in_sizes; (void)n_in; (void)out_size; (void)ws_size;
  const float* x    = (const float*)d_in[0];
  const float* ln1g = (const float*)d_in[1];
  const float* ln1b = (const float*)d_in[2];
  const float* wq   = (const float*)d_in[3];
  const float* bq   = (const float*)d_in[4];
  const float* wk   = (const float*)d_in[5];
  const float* bk   = (const float*)d_in[6];
  const float* wv   = (const float*)d_in[7];
  const float* bv   = (const float*)d_in[8];
  const float* wo   = (const float*)d_in[9];
  const float* bo   = (const float*)d_in[10];
  const float* ln2g = (const float*)d_in[11];
  const float* ln2b = (const float*)d_in[12];
  const float* w1   = (const float*)d_in[13];
  const float* b1   = (const float*)d_in[14];
  const float* w2   = (const float*)d_in[15];
  const float* b2   = (const float*)d_in[16];

  char* ws = (char*)d_ws;
  ushort_t* hb   = (ushort_t*)(ws);                          // [N,96]  bf16   50,331,648 B
  ushort_t* qkv  = (ushort_t*)(ws + 50331648);               // [N,288] bf16  150,994,944 B
  ushort_t* ob   = (ushort_t*)(ws + 50331648 + 150994944);   // [N,96]  bf16   50,331,648 B
  ushort_t* mb   = (ushort_t*)(ws + 50331648);               // [N,384] bf16 (aliases qkv+ob)
  char* wsw      = ws + 50331648 + 201326592;
  ushort_t* Wqkv = (ushort_t*)(wsw);                         // [288][96]
  ushort_t* Wo   = (ushort_t*)(wsw + 55296);                 // [96][96]
  ushort_t* W1   = (ushort_t*)(wsw + 55296 + 18432);         // [384][96]
  ushort_t* W2   = (ushort_t*)(wsw + 55296 + 18432 + 73728); // [96][384]
  float*    biasq= (float*)   (wsw + 55296 + 18432 + 73728 + 73728); // [288] fp32
  float* x2 = (float*)d_out;   // post-attention residual lives in d_out

  prep_kernel<<<434, 256, 0, stream>>>(wq, wk, wv, wo, w1, w2, bq, bk, bv,
                                       Wqkv, Wo, W1, W2, biasq);
  ln_kernel<<<NTOK / 4, 256, 0, stream>>>(x, ln1g, ln1b, hb);
  gemm_kernel<96, 3, 0><<<(NTOK / 16) * 3 / 4, 256, 0, stream>>>(hb, Wqkv, biasq, nullptr, qkv);
  attn_kernel<<<16384, 64, 0, stream>>>(qkv, ob);
  gemm_kernel<96, 1, 1><<<(NTOK / 16) / 4, 256, 0, stream>>>(ob, Wo, bo, x, x2);
  ln_kernel<<<NTOK / 4, 256, 0, stream>>>(x2, ln2g, ln2b, hb);
  gemm_kernel<96, 4, 2><<<(NTOK / 16) * 4 / 4, 256, 0, stream>>>(hb, W1, b1, nullptr, mb);
  gemm_kernel<384, 1, 1><<<(NTOK / 16) / 4, 256, 0, stream>>>(mb, W2, b2, x2, (float*)d_out);
}

// Round 2
// 549.800 us; speedup vs baseline: 1.3049x; 1.3049x over previous
//
#include <hip/hip_runtime.h>
#include <hip/hip_bf16.h>

typedef __attribute__((ext_vector_type(8))) short short8;
typedef __attribute__((ext_vector_type(4))) float f32x4;
typedef unsigned short ushort_t;

#define NTOK 262144   // B*D*H*W = 2*32*64*64

__device__ __forceinline__ ushort_t f2bf(float f){
  unsigned int x = __float_as_uint(f);
  unsigned int r = (x + 0x7fffu + ((x >> 16) & 1u)) >> 16;
  return (ushort_t)r;
}
__device__ __forceinline__ float gelu_exact(float x){
  return 0.5f * x * (1.0f + erff(x * 0.70710678118654752440f));
}

// ---------------- weight prep: fp32 -> bf16, transposed to Bt[col][k] ----------------
__global__ __launch_bounds__(256) void prep_kernel(
    const float* __restrict__ wq, const float* __restrict__ wk, const float* __restrict__ wv,
    const float* __restrict__ wo, const float* __restrict__ w1, const float* __restrict__ w2,
    const float* __restrict__ bq, const float* __restrict__ bk, const float* __restrict__ bv,
    ushort_t* __restrict__ Wqkv, ushort_t* __restrict__ Wo,
    ushort_t* __restrict__ W1, ushort_t* __restrict__ W2, float* __restrict__ biasq)
{
  int i = blockIdx.x * 256 + threadIdx.x;
  if (i < 27648) {                       // Wqkv_t[j][c], j = s*96 + h*24 + d
    int j = i / 96, c = i % 96;
    int s = j / 96, rem = j % 96;
    const float* src = (s == 0) ? wq : (s == 1) ? wk : wv;
    Wqkv[j * 96 + c] = f2bf(src[c * 96 + rem]);
  } else if (i < 36864) {                // Wo_t[c][hd] = wo[hd][c]
    int ii = i - 27648;
    int c = ii / 96, hd = ii % 96;
    Wo[ii] = f2bf(wo[hd * 96 + c]);
  } else if (i < 73728) {                // W1_t[j][c] = w1[c][j]
    int ii = i - 36864;
    int j = ii / 96, c = ii % 96;
    W1[ii] = f2bf(w1[c * 384 + j]);
  } else if (i < 110592) {               // W2_t[c][j] = w2[j][c]
    int ii = i - 73728;
    int c = ii / 384, j = ii % 384;
    W2[ii] = f2bf(w2[j * 96 + c]);
  } else if (i < 110880) {               // combined qkv bias (fp32)
    int j = i - 110592;
    int s = j / 96, rem = j % 96;
    const float* src = (s == 0) ? bq : (s == 1) ? bk : bv;
    biasq[j] = src[rem];
  }
}

// ---------------- LayerNorm: one wave per token (96 channels) ----------------
__global__ __launch_bounds__(256) void ln_kernel(const float* __restrict__ x,
    const float* __restrict__ g, const float* __restrict__ b, ushort_t* __restrict__ out)
{
  int wid = (blockIdx.x * 256 + threadIdx.x) >> 6;   // token id
  int lane = threadIdx.x & 63;
  const float* xp = x + (size_t)wid * 96;
  float a0 = xp[lane];
  float a1 = (lane < 32) ? xp[64 + lane] : 0.0f;
  float s = a0 + a1, sq = a0 * a0 + a1 * a1;
  #pragma unroll
  for (int off = 32; off > 0; off >>= 1) {
    s  += __shfl_xor(s, off);
    sq += __shfl_xor(sq, off);
  }
  float mean = s * (1.0f / 96.0f);
  float var  = sq * (1.0f / 96.0f) - mean * mean;
  float rstd = rsqrtf(var + 1e-5f);
  ushort_t* op = out + (size_t)wid * 96;
  op[lane] = f2bf((a0 - mean) * rstd * g[lane] + b[lane]);
  if (lane < 32)
    op[64 + lane] = f2bf((a1 - mean) * rstd * g[64 + lane] + b[64 + lane]);
}

// ---------------- MFMA GEMM (QKV): A[M,96]bf16 @ Bt[288,96]bf16 -> bf16 +bias ----------------
template<int K, int NTN>
__global__ __launch_bounds__(256) void gemm_kernel(const ushort_t* __restrict__ A,
    const ushort_t* __restrict__ Bt, const float* __restrict__ bias,
    ushort_t* __restrict__ out)
{
  constexpr int NOUT = NTN * 96;
  int gid  = blockIdx.x * 4 + (threadIdx.x >> 6);
  int lane = threadIdx.x & 63;
  int tile_n = gid % NTN;
  int tile_m = gid / NTN;

  int rA = tile_m * 16 + (lane & 15);
  const ushort_t* Ap = A + (size_t)rA * K + ((lane >> 4) * 8);
  int colB0 = tile_n * 96 + (lane & 15);
  const ushort_t* Bp = Bt + (size_t)colB0 * K + ((lane >> 4) * 8);

  f32x4 acc[6];
  #pragma unroll
  for (int j = 0; j < 6; j++) acc[j] = (f32x4){0.f, 0.f, 0.f, 0.f};

  #pragma unroll
  for (int k0 = 0; k0 < K; k0 += 32) {
    short8 a = *reinterpret_cast<const short8*>(Ap + k0);
    #pragma unroll
    for (int j = 0; j < 6; j++) {
      short8 bfr = *reinterpret_cast<const short8*>(Bp + (size_t)j * 16 * K + k0);
      acc[j] = __builtin_amdgcn_mfma_f32_16x16x32_bf16(a, bfr, acc[j], 0, 0, 0);
    }
  }

  int r0 = tile_m * 16 + ((lane >> 4) * 4);
  int c0 = tile_n * 96 + (lane & 15);
  #pragma unroll
  for (int j = 0; j < 6; j++) {
    int col = c0 + j * 16;
    float bs = bias[col];
    #pragma unroll
    for (int r = 0; r < 4; r++) {
      size_t row = (size_t)(r0 + r);
      out[row * NOUT + col] = f2bf(acc[j][r] + bs);
    }
  }
}

// ---------------- fused window attention + output projection ----------------
// 1 block = 1 window (64 tokens), 4 waves = 4 heads. MFMA throughout.
__global__ __launch_bounds__(256) void attn2_kernel(
    const ushort_t* __restrict__ qkv, const ushort_t* __restrict__ Wot,
    const float* __restrict__ bo, const float* __restrict__ xres,
    float* __restrict__ x2)
{
  __shared__ ushort_t Pb[4][64][72];   // P[q][k'] per head, stride 72 (16B-aligned, 2-way banks)
  __shared__ ushort_t Vt[4][32][72];   // V^T[d][k'] per head (rows 24..31 junk, never stored)
  ushort_t (*O_lds)[104] = reinterpret_cast<ushort_t (*)[104]>(&Pb[0][0][0]); // aliases Pb (post-barrier)

  int tid = threadIdx.x;
  int h = tid >> 6, lane = tid & 63, g = lane >> 4, l15 = lane & 15;
  int n = blockIdx.x;
  int wq_ = n & 15, hq = (n >> 4) & 15, rest = n >> 8;
  int dq = rest & 7, b = rest >> 3;
  int base = b * 131072 + dq * 16384 + hq * 256 + wq_ * 4;
  #define TOK(s) (base + ((s) >> 4) * 4096 + (((s) >> 2) & 3) * 64 + ((s) & 3))

  // ---- load V row (own token) and transpose into LDS ----
  {
    int t = TOK(lane);
    const ushort_t* vp = qkv + (size_t)t * 288 + 192 + h * 24;
    short8 v0 = *(const short8*)(vp);
    short8 v1 = *(const short8*)(vp + 8);
    short8 v2 = *(const short8*)(vp + 16);
    #pragma unroll
    for (int d = 0; d < 8; d++) Vt[h][d][lane]      = (ushort_t)v0[d];
    #pragma unroll
    for (int d = 0; d < 8; d++) Vt[h][8 + d][lane]  = (ushort_t)v1[d];
    #pragma unroll
    for (int d = 0; d < 8; d++) Vt[h][16 + d][lane] = (ushort_t)v2[d];
  }

  // ---- K/Q fragments straight from global (k-dim 24, group 3 zeroed) ----
  short8 kf[4], qf[4];
  const short8 z8 = {0, 0, 0, 0, 0, 0, 0, 0};
  #pragma unroll
  for (int i = 0; i < 4; i++) {
    int t = TOK(i * 16 + l15);
    const ushort_t* rp = qkv + (size_t)t * 288 + h * 24 + g * 8;
    qf[i] = (g < 3) ? *(const short8*)(rp)      : z8;
    kf[i] = (g < 3) ? *(const short8*)(rp + 96) : z8;
  }

  // ---- S^T = K @ Q^T : D[i=k'][j=q] ----
  f32x4 st[4][4];
  #pragma unroll
  for (int tm = 0; tm < 4; tm++)
    #pragma unroll
    for (int tn = 0; tn < 4; tn++)
      st[tm][tn] = __builtin_amdgcn_mfma_f32_16x16x32_bf16(kf[tm], qf[tn],
                    (f32x4){0.f, 0.f, 0.f, 0.f}, 0, 0, 0);

  // ---- softmax over k' (16 in-lane values + shfl over lanes ^16,^32), write P bf16 ----
  const float scale = 0.20412414523193150818f;  // 1/sqrt(24)
  #pragma unroll
  for (int tn = 0; tn < 4; tn++) {
    float m = st[0][tn][0];
    #pragma unroll
    for (int tm = 0; tm < 4; tm++)
      #pragma unroll
      for (int r = 0; r < 4; r++) m = fmaxf(m, st[tm][tn][r]);
    m = fmaxf(m, __shfl_xor(m, 16));
    m = fmaxf(m, __shfl_xor(m, 32));
    float sum = 0.f;
    #pragma unroll
    for (int tm = 0; tm < 4; tm++)
      #pragma unroll
      for (int r = 0; r < 4; r++) {
        float e = __expf((st[tm][tn][r] - m) * scale);
        st[tm][tn][r] = e;
        sum += e;
      }
    sum += __shfl_xor(sum, 16);
    sum += __shfl_xor(sum, 32);
    float inv = 1.0f / sum;
    int q = tn * 16 + l15;
    #pragma unroll
    for (int tm = 0; tm < 4; tm++) {
      unsigned lo = (unsigned)f2bf(st[tm][tn][0] * inv) | ((unsigned)f2bf(st[tm][tn][1] * inv) << 16);
      unsigned hi = (unsigned)f2bf(st[tm][tn][2] * inv) | ((unsigned)f2bf(st[tm][tn][3] * inv) << 16);
      uint2 pk; pk.x = lo; pk.y = hi;
      *(uint2*)&Pb[h][q][tm * 16 + g * 4] = pk;
    }
  }

  // ---- O = P @ V : D[i=q][j=d] (within-wave LDS RAW, lgkmcnt-ordered) ----
  f32x4 oacc[4][2];
  #pragma unroll
  for (int qt = 0; qt < 4; qt++)
    #pragma unroll
    for (int dt = 0; dt < 2; dt++) oacc[qt][dt] = (f32x4){0.f, 0.f, 0.f, 0.f};
  #pragma unroll
  for (int ks = 0; ks < 2; ks++) {
    short8 vb[2];
    #pragma unroll
    for (int dt = 0; dt < 2; dt++)
      vb[dt] = *(const short8*)&Vt[h][dt * 16 + l15][ks * 32 + g * 8];
    #pragma unroll
    for (int qt = 0; qt < 4; qt++) {
      short8 pa = *(const short8*)&Pb[h][qt * 16 + l15][ks * 32 + g * 8];
      #pragma unroll
      for (int dt = 0; dt < 2; dt++)
        oacc[qt][dt] = __builtin_amdgcn_mfma_f32_16x16x32_bf16(pa, vb[dt], oacc[qt][dt], 0, 0, 0);
    }
  }

  __syncthreads();                 // everyone done reading Pb/Vt
  // ---- stage O (64 x 96 bf16) into LDS (overlays Pb) ----
  #pragma unroll
  for (int qt = 0; qt < 4; qt++)
    #pragma unroll
    for (int dt = 0; dt < 2; dt++) {
      int d = dt * 16 + l15;
      if (d < 24) {
        #pragma unroll
        for (int r = 0; r < 4; r++)
          O_lds[qt * 16 + g * 4 + r][h * 24 + d] = f2bf(oacc[qt][dt][r]);
      }
    }
  __syncthreads();

  // ---- projection: rows w*16..w*16+15, O[64,96] @ Wo_t[96,96] + bo + residual ----
  int w = h;
  f32x4 pacc[6];
  #pragma unroll
  for (int nt = 0; nt < 6; nt++) pacc[nt] = (f32x4){0.f, 0.f, 0.f, 0.f};
  #pragma unroll
  for (int ks = 0; ks < 3; ks++) {
    short8 pa = *(const short8*)&O_lds[w * 16 + l15][ks * 32 + g * 8];
    #pragma unroll
    for (int nt = 0; nt < 6; nt++) {
      short8 wb = *(const short8*)&Wot[(size_t)(nt * 16 + l15) * 96 + ks * 32 + g * 8];
      pacc[nt] = __builtin_amdgcn_mfma_f32_16x16x32_bf16(pa, wb, pacc[nt], 0, 0, 0);
    }
  }
  #pragma unroll
  for (int nt = 0; nt < 6; nt++) {
    int col = nt * 16 + l15;
    float bs = bo[col];
    #pragma unroll
    for (int r = 0; r < 4; r++) {
      int s = w * 16 + g * 4 + r;
      size_t t = (size_t)TOK(s);
      float v = pacc[nt][r] + bs + xres[t * 96 + col];
      x2[t * 96 + col] = v;
    }
  }
  #undef TOK
}

// ---------------- fused MLP: h@W1+b1 -> gelu -> @W2+b2 + residual ----------------
// 1 block = 64 rows, 4 waves x 16 rows; mid staged in LDS.
__global__ __launch_bounds__(256) void mlp_kernel(
    const ushort_t* __restrict__ hb, const ushort_t* __restrict__ W1t,
    const float* __restrict__ b1, const ushort_t* __restrict__ W2t,
    const float* __restrict__ b2, const float* __restrict__ res,
    float* __restrict__ out)
{
  __shared__ ushort_t mid[64][392];   // stride 392: 16B-aligned rows, 2-way banks
  int tid = threadIdx.x, w = tid >> 6, lane = tid & 63, g = lane >> 4, l15 = lane & 15;
  size_t r0 = (size_t)blockIdx.x * 64 + w * 16;

  short8 af[3];
  #pragma unroll
  for (int ks = 0; ks < 3; ks++)
    af[ks] = *(const short8*)&hb[(r0 + l15) * 96 + ks * 32 + g * 8];

  #pragma unroll
  for (int nt = 0; nt < 24; nt++) {
    f32x4 acc = (f32x4){0.f, 0.f, 0.f, 0.f};
    #pragma unroll
    for (int ks = 0; ks < 3; ks++) {
      short8 bfr = *(const short8*)&W1t[(size_t)(nt * 16 + l15) * 96 + ks * 32 + g * 8];
      acc = __builtin_amdgcn_mfma_f32_16x16x32_bf16(af[ks], bfr, acc, 0, 0, 0);
    }
    int col = nt * 16 + l15;
    float bs = b1[col];
    #pragma unroll
    for (int r = 0; r < 4; r++)
      mid[w * 16 + g * 4 + r][col] = f2bf(gelu_exact(acc[r] + bs));
  }
  __syncthreads();

  f32x4 acc2[6];
  #pragma unroll
  for (int nt = 0; nt < 6; nt++) acc2[nt] = (f32x4){0.f, 0.f, 0.f, 0.f};
  #pragma unroll
  for (int ks = 0; ks < 12; ks++) {
    short8 a2 = *(const short8*)&mid[w * 16 + l15][ks * 32 + g * 8];
    #pragma unroll
    for (int nt = 0; nt < 6; nt++) {
      short8 b2f = *(const short8*)&W2t[(size_t)(nt * 16 + l15) * 384 + ks * 32 + g * 8];
      acc2[nt] = __builtin_amdgcn_mfma_f32_16x16x32_bf16(a2, b2f, acc2[nt], 0, 0, 0);
    }
  }
  #pragma unroll
  for (int nt = 0; nt < 6; nt++) {
    int col = nt * 16 + l15;
    float bs = b2[col];
    #pragma unroll
    for (int r = 0; r < 4; r++) {
      size_t row = r0 + g * 4 + r;
      float v = acc2[nt][r] + bs + res[row * 96 + col];
      out[row * 96 + col] = v;
    }
  }
}

// ---------------- launch ----------------
extern "C" void kernel_launch(void* const* d_in, const int* in_sizes, int n_in,
                              void* d_out, int out_size, void* d_ws, size_t ws_size,
                              hipStream_t stream)
{
  (void)in_sizes; (void)n_in; (void)out_size; (void)ws_size;
  const float* x    = (const float*)d_in[0];
  const float* ln1g = (const float*)d_in[1];
  const float* ln1b = (const float*)d_in[2];
  const float* wq   = (const float*)d_in[3];
  const float* bq   = (const float*)d_in[4];
  const float* wk   = (const float*)d_in[5];
  const float* bk   = (const float*)d_in[6];
  const float* wv   = (const float*)d_in[7];
  const float* bv   = (const float*)d_in[8];
  const float* wo   = (const float*)d_in[9];
  const float* bo   = (const float*)d_in[10];
  const float* ln2g = (const float*)d_in[11];
  const float* ln2b = (const float*)d_in[12];
  const float* w1   = (const float*)d_in[13];
  const float* b1   = (const float*)d_in[14];
  const float* w2   = (const float*)d_in[15];
  const float* b2   = (const float*)d_in[16];

  char* ws = (char*)d_ws;
  ushort_t* hb   = (ushort_t*)(ws);                          // [N,96]  bf16   50,331,648 B
  ushort_t* qkv  = (ushort_t*)(ws + 50331648);               // [N,288] bf16  150,994,944 B
  char* wsw      = ws + 50331648 + 150994944;
  ushort_t* Wqkv = (ushort_t*)(wsw);                         // [288][96]
  ushort_t* Wo   = (ushort_t*)(wsw + 55296);                 // [96][96]
  ushort_t* W1   = (ushort_t*)(wsw + 55296 + 18432);         // [384][96]
  ushort_t* W2   = (ushort_t*)(wsw + 55296 + 18432 + 73728); // [96][384]
  float*    biasq= (float*)   (wsw + 55296 + 18432 + 73728 + 73728); // [288] fp32
  float* x2 = (float*)d_out;   // post-attention residual lives in d_out

  prep_kernel<<<434, 256, 0, stream>>>(wq, wk, wv, wo, w1, w2, bq, bk, bv,
                                       Wqkv, Wo, W1, W2, biasq);
  ln_kernel<<<NTOK / 4, 256, 0, stream>>>(x, ln1g, ln1b, hb);
  gemm_kernel<96, 3><<<(NTOK / 16) * 3 / 4, 256, 0, stream>>>(hb, Wqkv, biasq, qkv);
  attn2_kernel<<<4096, 256, 0, stream>>>(qkv, Wo, bo, x, x2);
  ln_kernel<<<NTOK / 4, 256, 0, stream>>>(x2, ln2g, ln2b, hb);
  mlp_kernel<<<4096, 256, 0, stream>>>(hb, W1, b1, W2, b2, x2, (float*)d_out);
}

// Round 3
// 394.474 us; speedup vs baseline: 1.8188x; 1.3938x over previous
//
#include <hip/hip_runtime.h>
#include <hip/hip_bf16.h>

typedef __attribute__((ext_vector_type(8))) short short8;
typedef __attribute__((ext_vector_type(4))) float f32x4;
typedef unsigned short ushort_t;

#define NTOK 262144   // B*D*H*W = 2*32*64*64

__device__ __forceinline__ ushort_t f2bf(float f){
  unsigned int x = __float_as_uint(f);
  unsigned int r = (x + 0x7fffu + ((x >> 16) & 1u)) >> 16;
  return (ushort_t)r;
}
__device__ __forceinline__ float gelu_exact(float x){
  return 0.5f * x * (1.0f + erff(x * 0.70710678118654752440f));
}

// ---------------- weight prep: fp32 -> bf16, transposed to Bt[col][k] ----------------
__global__ __launch_bounds__(256) void prep_kernel(
    const float* __restrict__ wq, const float* __restrict__ wk, const float* __restrict__ wv,
    const float* __restrict__ wo, const float* __restrict__ w1, const float* __restrict__ w2,
    const float* __restrict__ bq, const float* __restrict__ bk, const float* __restrict__ bv,
    ushort_t* __restrict__ Wqkv, ushort_t* __restrict__ Wo,
    ushort_t* __restrict__ W1, ushort_t* __restrict__ W2, float* __restrict__ biasq)
{
  int i = blockIdx.x * 256 + threadIdx.x;
  if (i < 27648) {                       // Wqkv_t[j][c], j = s*96 + h*24 + d
    int j = i / 96, c = i % 96;
    int s = j / 96, rem = j % 96;
    const float* src = (s == 0) ? wq : (s == 1) ? wk : wv;
    Wqkv[j * 96 + c] = f2bf(src[c * 96 + rem]);
  } else if (i < 36864) {                // Wo_t[c][hd] = wo[hd][c]
    int ii = i - 27648;
    int c = ii / 96, hd = ii % 96;
    Wo[ii] = f2bf(wo[hd * 96 + c]);
  } else if (i < 73728) {                // W1_t[j][c] = w1[c][j]
    int ii = i - 36864;
    int j = ii / 96, c = ii % 96;
    W1[ii] = f2bf(w1[c * 384 + j]);
  } else if (i < 110592) {               // W2_t[c][j] = w2[j][c]
    int ii = i - 73728;
    int c = ii / 384, j = ii % 384;
    W2[ii] = f2bf(w2[j * 96 + c]);
  } else if (i < 110880) {               // combined qkv bias (fp32)
    int j = i - 110592;
    int s = j / 96, rem = j % 96;
    const float* src = (s == 0) ? bq : (s == 1) ? bk : bv;
    biasq[j] = src[rem];
  }
}

// ---- per-thread half-row LN into LDS tile hbt[128][104] (bf16) ----
// thread t: row r0 + (t>>1), channels (t&1)*48 .. +47; pair-combined via shfl_xor(1).
__device__ __forceinline__ void ln_to_lds(const float* __restrict__ xrow_base,
    const float* __restrict__ gg, const float* __restrict__ bb,
    ushort_t (*hbt)[104], int tid)
{
  int row = tid >> 1, half = tid & 1;
  const float* xp = xrow_base + (size_t)row * 96 + half * 48;
  f32x4 v[12];
  float s = 0.f, sq = 0.f;
  #pragma unroll
  for (int i = 0; i < 12; i++) {
    v[i] = *reinterpret_cast<const f32x4*>(xp + i * 4);
    #pragma unroll
    for (int j = 0; j < 4; j++) { s += v[i][j]; sq += v[i][j] * v[i][j]; }
  }
  s  += __shfl_xor(s, 1);
  sq += __shfl_xor(sq, 1);
  float mean = s * (1.0f / 96.0f);
  float var  = sq * (1.0f / 96.0f) - mean * mean;
  float rstd = rsqrtf(var + 1e-5f);
  #pragma unroll
  for (int i8 = 0; i8 < 6; i8++) {
    short8 pk;
    #pragma unroll
    for (int j = 0; j < 8; j++) {
      int c = half * 48 + i8 * 8 + j;
      pk[j] = (short)f2bf((v[(i8 * 8 + j) >> 2][(i8 * 8 + j) & 3] - mean) * rstd * gg[c] + bb[c]);
    }
    *reinterpret_cast<short8*>(&hbt[row][half * 48 + i8 * 8]) = pk;
  }
}

// ---------------- fused LN1 + QKV projection ----------------
// block = 128 rows, 4 waves x (2 m-tiles of 16 rows). B-frags from L2, 2 MFMAs per load.
__global__ __launch_bounds__(256) void lnqkv_kernel(const float* __restrict__ x,
    const float* __restrict__ g, const float* __restrict__ b,
    const ushort_t* __restrict__ Wt, const float* __restrict__ biasq,
    ushort_t* __restrict__ qkv)
{
  __shared__ ushort_t hbt[128][104];
  int tid = threadIdx.x;
  size_t r0 = (size_t)blockIdx.x * 128;
  ln_to_lds(x + r0 * 96, g, b, hbt, tid);
  __syncthreads();

  int w = tid >> 6, lane = tid & 63, g16 = lane >> 4, l15 = lane & 15;
  short8 af[2][3];
  #pragma unroll
  for (int mi = 0; mi < 2; mi++)
    #pragma unroll
    for (int ks = 0; ks < 3; ks++)
      af[mi][ks] = *reinterpret_cast<const short8*>(&hbt[w * 32 + mi * 16 + l15][ks * 32 + g16 * 8]);

  #pragma unroll
  for (int nt = 0; nt < 18; nt++) {
    f32x4 acc[2];
    acc[0] = (f32x4){0.f, 0.f, 0.f, 0.f};
    acc[1] = (f32x4){0.f, 0.f, 0.f, 0.f};
    #pragma unroll
    for (int ks = 0; ks < 3; ks++) {
      short8 bfr = *reinterpret_cast<const short8*>(&Wt[(size_t)(nt * 16 + l15) * 96 + ks * 32 + g16 * 8]);
      acc[0] = __builtin_amdgcn_mfma_f32_16x16x32_bf16(af[0][ks], bfr, acc[0], 0, 0, 0);
      acc[1] = __builtin_amdgcn_mfma_f32_16x16x32_bf16(af[1][ks], bfr, acc[1], 0, 0, 0);
    }
    int col = nt * 16 + l15;
    float bs = biasq[col];
    #pragma unroll
    for (int mi = 0; mi < 2; mi++)
      #pragma unroll
      for (int r = 0; r < 4; r++)
        qkv[(r0 + w * 32 + mi * 16 + g16 * 4 + r) * 288 + col] = f2bf(acc[mi][r] + bs);
  }
}

// ---------------- fused window attention + output projection ----------------
// 1 block = 1 window (64 tokens), 4 waves = 4 heads. MFMA throughout.
__global__ __launch_bounds__(256) void attn2_kernel(
    const ushort_t* __restrict__ qkv, const ushort_t* __restrict__ Wot,
    const float* __restrict__ bo, const float* __restrict__ xres,
    float* __restrict__ x2)
{
  __shared__ ushort_t Pb[4][64][72];   // P[q][k'] per head, stride 72 (16B-aligned, 2-way banks)
  __shared__ ushort_t Vt[4][32][72];   // V^T[d][k'] per head (rows 24..31 junk, never stored)
  ushort_t (*O_lds)[104] = reinterpret_cast<ushort_t (*)[104]>(&Pb[0][0][0]); // aliases Pb (post-barrier)

  int tid = threadIdx.x;
  int h = tid >> 6, lane = tid & 63, g = lane >> 4, l15 = lane & 15;
  int n = blockIdx.x;
  int wq_ = n & 15, hq = (n >> 4) & 15, rest = n >> 8;
  int dq = rest & 7, b = rest >> 3;
  int base = b * 131072 + dq * 16384 + hq * 256 + wq_ * 4;
  #define TOK(s) (base + ((s) >> 4) * 4096 + (((s) >> 2) & 3) * 64 + ((s) & 3))

  // ---- load V row (own token) and transpose into LDS ----
  {
    int t = TOK(lane);
    const ushort_t* vp = qkv + (size_t)t * 288 + 192 + h * 24;
    short8 v0 = *(const short8*)(vp);
    short8 v1 = *(const short8*)(vp + 8);
    short8 v2 = *(const short8*)(vp + 16);
    #pragma unroll
    for (int d = 0; d < 8; d++) Vt[h][d][lane]      = (ushort_t)v0[d];
    #pragma unroll
    for (int d = 0; d < 8; d++) Vt[h][8 + d][lane]  = (ushort_t)v1[d];
    #pragma unroll
    for (int d = 0; d < 8; d++) Vt[h][16 + d][lane] = (ushort_t)v2[d];
  }

  // ---- K/Q fragments straight from global (k-dim 24, group 3 zeroed) ----
  short8 kf[4], qf[4];
  const short8 z8 = {0, 0, 0, 0, 0, 0, 0, 0};
  #pragma unroll
  for (int i = 0; i < 4; i++) {
    int t = TOK(i * 16 + l15);
    const ushort_t* rp = qkv + (size_t)t * 288 + h * 24 + g * 8;
    qf[i] = (g < 3) ? *(const short8*)(rp)      : z8;
    kf[i] = (g < 3) ? *(const short8*)(rp + 96) : z8;
  }

  // ---- S^T = K @ Q^T : D[i=k'][j=q] ----
  f32x4 st[4][4];
  #pragma unroll
  for (int tm = 0; tm < 4; tm++)
    #pragma unroll
    for (int tn = 0; tn < 4; tn++)
      st[tm][tn] = __builtin_amdgcn_mfma_f32_16x16x32_bf16(kf[tm], qf[tn],
                    (f32x4){0.f, 0.f, 0.f, 0.f}, 0, 0, 0);

  // ---- softmax over k' (16 in-lane values + shfl over lanes ^16,^32), write P bf16 ----
  const float scale = 0.20412414523193150818f;  // 1/sqrt(24)
  #pragma unroll
  for (int tn = 0; tn < 4; tn++) {
    float m = st[0][tn][0];
    #pragma unroll
    for (int tm = 0; tm < 4; tm++)
      #pragma unroll
      for (int r = 0; r < 4; r++) m = fmaxf(m, st[tm][tn][r]);
    m = fmaxf(m, __shfl_xor(m, 16));
    m = fmaxf(m, __shfl_xor(m, 32));
    float sum = 0.f;
    #pragma unroll
    for (int tm = 0; tm < 4; tm++)
      #pragma unroll
      for (int r = 0; r < 4; r++) {
        float e = __expf((st[tm][tn][r] - m) * scale);
        st[tm][tn][r] = e;
        sum += e;
      }
    sum += __shfl_xor(sum, 16);
    sum += __shfl_xor(sum, 32);
    float inv = 1.0f / sum;
    int q = tn * 16 + l15;
    #pragma unroll
    for (int tm = 0; tm < 4; tm++) {
      unsigned lo = (unsigned)f2bf(st[tm][tn][0] * inv) | ((unsigned)f2bf(st[tm][tn][1] * inv) << 16);
      unsigned hi = (unsigned)f2bf(st[tm][tn][2] * inv) | ((unsigned)f2bf(st[tm][tn][3] * inv) << 16);
      uint2 pk; pk.x = lo; pk.y = hi;
      *(uint2*)&Pb[h][q][tm * 16 + g * 4] = pk;
    }
  }

  // ---- O = P @ V : D[i=q][j=d] (within-wave LDS RAW, lgkmcnt-ordered) ----
  f32x4 oacc[4][2];
  #pragma unroll
  for (int qt = 0; qt < 4; qt++)
    #pragma unroll
    for (int dt = 0; dt < 2; dt++) oacc[qt][dt] = (f32x4){0.f, 0.f, 0.f, 0.f};
  #pragma unroll
  for (int ks = 0; ks < 2; ks++) {
    short8 vb[2];
    #pragma unroll
    for (int dt = 0; dt < 2; dt++)
      vb[dt] = *(const short8*)&Vt[h][dt * 16 + l15][ks * 32 + g * 8];
    #pragma unroll
    for (int qt = 0; qt < 4; qt++) {
      short8 pa = *(const short8*)&Pb[h][qt * 16 + l15][ks * 32 + g * 8];
      #pragma unroll
      for (int dt = 0; dt < 2; dt++)
        oacc[qt][dt] = __builtin_amdgcn_mfma_f32_16x16x32_bf16(pa, vb[dt], oacc[qt][dt], 0, 0, 0);
    }
  }

  __syncthreads();                 // everyone done reading Pb/Vt
  // ---- stage O (64 x 96 bf16) into LDS (overlays Pb) ----
  #pragma unroll
  for (int qt = 0; qt < 4; qt++)
    #pragma unroll
    for (int dt = 0; dt < 2; dt++) {
      int d = dt * 16 + l15;
      if (d < 24) {
        #pragma unroll
        for (int r = 0; r < 4; r++)
          O_lds[qt * 16 + g * 4 + r][h * 24 + d] = f2bf(oacc[qt][dt][r]);
      }
    }
  __syncthreads();

  // ---- projection: rows w*16..w*16+15, O[64,96] @ Wo_t[96,96] + bo + residual ----
  int w = h;
  f32x4 pacc[6];
  #pragma unroll
  for (int nt = 0; nt < 6; nt++) pacc[nt] = (f32x4){0.f, 0.f, 0.f, 0.f};
  #pragma unroll
  for (int ks = 0; ks < 3; ks++) {
    short8 pa = *(const short8*)&O_lds[w * 16 + l15][ks * 32 + g * 8];
    #pragma unroll
    for (int nt = 0; nt < 6; nt++) {
      short8 wb = *(const short8*)&Wot[(size_t)(nt * 16 + l15) * 96 + ks * 32 + g * 8];
      pacc[nt] = __builtin_amdgcn_mfma_f32_16x16x32_bf16(pa, wb, pacc[nt], 0, 0, 0);
    }
  }
  #pragma unroll
  for (int nt = 0; nt < 6; nt++) {
    int col = nt * 16 + l15;
    float bs = bo[col];
    #pragma unroll
    for (int r = 0; r < 4; r++) {
      int s = w * 16 + g * 4 + r;
      size_t t = (size_t)TOK(s);
      float v = pacc[nt][r] + bs + xres[t * 96 + col];
      x2[t * 96 + col] = v;
    }
  }
  #undef TOK
}

// ---------------- fused LN2 + MLP + residual ----------------
// block = 128 rows, 4 waves x (2 m-tiles). mid chunked 4 x 96 cols through LDS.
__global__ __launch_bounds__(256) void mlp2_kernel(
    const float* __restrict__ x2, const float* __restrict__ g, const float* __restrict__ b,
    const ushort_t* __restrict__ W1t, const float* __restrict__ b1,
    const ushort_t* __restrict__ W2t, const float* __restrict__ b2,
    float* __restrict__ out)
{
  __shared__ ushort_t hbt[128][104];
  __shared__ ushort_t mid[128][104];
  int tid = threadIdx.x;
  size_t r0 = (size_t)blockIdx.x * 128;
  ln_to_lds(x2 + r0 * 96, g, b, hbt, tid);
  __syncthreads();

  int w = tid >> 6, lane = tid & 63, g16 = lane >> 4, l15 = lane & 15;
  short8 af[2][3];
  #pragma unroll
  for (int mi = 0; mi < 2; mi++)
    #pragma unroll
    for (int ks = 0; ks < 3; ks++)
      af[mi][ks] = *reinterpret_cast<const short8*>(&hbt[w * 32 + mi * 16 + l15][ks * 32 + g16 * 8]);

  f32x4 oacc[2][6];
  #pragma unroll
  for (int mi = 0; mi < 2; mi++)
    #pragma unroll
    for (int nt = 0; nt < 6; nt++) oacc[mi][nt] = (f32x4){0.f, 0.f, 0.f, 0.f};

  #pragma unroll
  for (int cc = 0; cc < 4; cc++) {
    // phase 1: mid[:, cc*96 .. +95] = gelu(hbt @ W1t_chunk + b1)
    #pragma unroll
    for (int ntl = 0; ntl < 6; ntl++) {
      f32x4 acc[2];
      acc[0] = (f32x4){0.f, 0.f, 0.f, 0.f};
      acc[1] = (f32x4){0.f, 0.f, 0.f, 0.f};
      #pragma unroll
      for (int ks = 0; ks < 3; ks++) {
        short8 bfr = *reinterpret_cast<const short8*>(
            &W1t[(size_t)(cc * 96 + ntl * 16 + l15) * 96 + ks * 32 + g16 * 8]);
        acc[0] = __builtin_amdgcn_mfma_f32_16x16x32_bf16(af[0][ks], bfr, acc[0], 0, 0, 0);
        acc[1] = __builtin_amdgcn_mfma_f32_16x16x32_bf16(af[1][ks], bfr, acc[1], 0, 0, 0);
      }
      int colg = cc * 96 + ntl * 16 + l15;
      float bs = b1[colg];
      #pragma unroll
      for (int mi = 0; mi < 2; mi++)
        #pragma unroll
        for (int r = 0; r < 4; r++)
          mid[w * 32 + mi * 16 + g16 * 4 + r][ntl * 16 + l15] = f2bf(gelu_exact(acc[mi][r] + bs));
    }
    __syncthreads();
    // phase 2: oacc += mid_chunk @ W2t_chunk
    short8 a2[2][3];
    #pragma unroll
    for (int mi = 0; mi < 2; mi++)
      #pragma unroll
      for (int ks = 0; ks < 3; ks++)
        a2[mi][ks] = *reinterpret_cast<const short8*>(&mid[w * 32 + mi * 16 + l15][ks * 32 + g16 * 8]);
    __syncthreads();   // a2 in regs; next chunk may overwrite mid
    #pragma unroll
    for (int ntl = 0; ntl < 6; ntl++) {
      #pragma unroll
      for (int ks = 0; ks < 3; ks++) {
        short8 b2f = *reinterpret_cast<const short8*>(
            &W2t[(size_t)(ntl * 16 + l15) * 384 + cc * 96 + ks * 32 + g16 * 8]);
        oacc[0][ntl] = __builtin_amdgcn_mfma_f32_16x16x32_bf16(a2[0][ks], b2f, oacc[0][ntl], 0, 0, 0);
        oacc[1][ntl] = __builtin_amdgcn_mfma_f32_16x16x32_bf16(a2[1][ks], b2f, oacc[1][ntl], 0, 0, 0);
      }
    }
  }

  // epilogue: out = oacc + b2 + residual(x2)
  #pragma unroll
  for (int ntl = 0; ntl < 6; ntl++) {
    int col = ntl * 16 + l15;
    float bs = b2[col];
    #pragma unroll
    for (int mi = 0; mi < 2; mi++)
      #pragma unroll
      for (int r = 0; r < 4; r++) {
        size_t row = r0 + w * 32 + mi * 16 + g16 * 4 + r;
        out[row * 96 + col] = oacc[mi][ntl][r] + bs + x2[row * 96 + col];
      }
  }
}

// ---------------- launch ----------------
extern "C" void kernel_launch(void* const* d_in, const int* in_sizes, int n_in,
                              void* d_out, int out_size, void* d_ws, size_t ws_size,
                              hipStream_t stream)
{
  (void)in_sizes; (void)n_in; (void)out_size; (void)ws_size;
  const float* x    = (const float*)d_in[0];
  const float* ln1g = (const float*)d_in[1];
  const float* ln1b = (const float*)d_in[2];
  const float* wq   = (const float*)d_in[3];
  const float* bq   = (const float*)d_in[4];
  const float* wk   = (const float*)d_in[5];
  const float* bk   = (const float*)d_in[6];
  const float* wv   = (const float*)d_in[7];
  const float* bv   = (const float*)d_in[8];
  const float* wo   = (const float*)d_in[9];
  const float* bo   = (const float*)d_in[10];
  const float* ln2g = (const float*)d_in[11];
  const float* ln2b = (const float*)d_in[12];
  const float* w1   = (const float*)d_in[13];
  const float* b1   = (const float*)d_in[14];
  const float* w2   = (const float*)d_in[15];
  const float* b2   = (const float*)d_in[16];

  char* ws = (char*)d_ws;
  ushort_t* qkv  = (ushort_t*)(ws);                          // [N,288] bf16  150,994,944 B
  char* wsw      = ws + 150994944;
  ushort_t* Wqkv = (ushort_t*)(wsw);                         // [288][96]
  ushort_t* Wo   = (ushort_t*)(wsw + 55296);                 // [96][96]
  ushort_t* W1   = (ushort_t*)(wsw + 55296 + 18432);         // [384][96]
  ushort_t* W2   = (ushort_t*)(wsw + 55296 + 18432 + 73728); // [96][384]
  float*    biasq= (float*)   (wsw + 55296 + 18432 + 73728 + 73728); // [288] fp32
  float* x2 = (float*)d_out;   // post-attention residual lives in d_out

  prep_kernel<<<434, 256, 0, stream>>>(wq, wk, wv, wo, w1, w2, bq, bk, bv,
                                       Wqkv, Wo, W1, W2, biasq);
  lnqkv_kernel<<<NTOK / 128, 256, 0, stream>>>(x, ln1g, ln1b, Wqkv, biasq, qkv);
  attn2_kernel<<<4096, 256, 0, stream>>>(qkv, Wo, bo, x, x2);
  mlp2_kernel<<<NTOK / 128, 256, 0, stream>>>(x2, ln2g, ln2b, W1, b1, W2, b2, (float*)d_out);
}

// Round 5
// 319.312 us; speedup vs baseline: 2.2469x; 1.2354x over previous
//
#include <hip/hip_runtime.h>
#include <hip/hip_bf16.h>

typedef __attribute__((ext_vector_type(8))) short short8;
typedef __attribute__((ext_vector_type(4))) float f32x4;
typedef unsigned short ushort_t;

#define NTOK 262144   // B*D*H*W = 2*32*64*64

__device__ __forceinline__ ushort_t f2bf(float f){
  unsigned int x = __float_as_uint(f);
  unsigned int r = (x + 0x7fffu + ((x >> 16) & 1u)) >> 16;
  return (ushort_t)r;
}
// exact-erf gelu via Abramowitz-Stegun 7.1.26 (|err| <= 1.5e-7), branch-free
__device__ __forceinline__ float gelu_exact(float x){
  float u = fabsf(x) * 0.70710678118654752440f;
  float t = 1.0f / (1.0f + 0.3275911f * u);
  float poly = t * (0.254829592f + t * (-0.284496736f + t * (1.421413741f +
               t * (-1.453152027f + t * 1.061405429f))));
  float e = __expf(-u * u);
  float er = copysignf(1.0f - poly * e, x);
  return 0.5f * x * (1.0f + er);
}
// LDS-only barrier: do NOT drain vmcnt (keeps global prefetches in flight)
__device__ __forceinline__ void bar_lds(){
  asm volatile("s_waitcnt lgkmcnt(0)" ::: "memory");
  __builtin_amdgcn_s_barrier();
}

// ---------------- weight prep: fp32 -> bf16, transposed to Bt[col][k] ----------------
__global__ __launch_bounds__(256) void prep_kernel(
    const float* __restrict__ wq, const float* __restrict__ wk, const float* __restrict__ wv,
    const float* __restrict__ wo, const float* __restrict__ w1, const float* __restrict__ w2,
    const float* __restrict__ bq, const float* __restrict__ bk, const float* __restrict__ bv,
    ushort_t* __restrict__ Wqkv, ushort_t* __restrict__ Wo,
    ushort_t* __restrict__ W1, ushort_t* __restrict__ W2, float* __restrict__ biasq)
{
  int i = blockIdx.x * 256 + threadIdx.x;
  if (i < 27648) {                       // Wqkv_t[j][c], j = s*96 + h*24 + d
    int j = i / 96, c = i % 96;
    int s = j / 96, rem = j % 96;
    const float* src = (s == 0) ? wq : (s == 1) ? wk : wv;
    Wqkv[j * 96 + c] = f2bf(src[c * 96 + rem]);
  } else if (i < 36864) {                // Wo_t[c][hd] = wo[hd][c]
    int ii = i - 27648;
    int c = ii / 96, hd = ii % 96;
    Wo[ii] = f2bf(wo[hd * 96 + c]);
  } else if (i < 73728) {                // W1_t[j][c] = w1[c][j]
    int ii = i - 36864;
    int j = ii / 96, c = ii % 96;
    W1[ii] = f2bf(w1[c * 384 + j]);
  } else if (i < 110592) {               // W2_t[c][j] = w2[j][c]
    int ii = i - 73728;
    int c = ii / 384, j = ii % 384;
    W2[ii] = f2bf(w2[j * 96 + c]);
  } else if (i < 110880) {               // combined qkv bias (fp32)
    int j = i - 110592;
    int s = j / 96, rem = j % 96;
    const float* src = (s == 0) ? bq : (s == 1) ? bk : bv;
    biasq[j] = src[rem];
  }
}

// ---- per-thread half-row LN into LDS tile hbt[128][104] (bf16) ----
__device__ __forceinline__ void ln_to_lds(const float* __restrict__ xrow_base,
    const float* __restrict__ gg, const float* __restrict__ bb,
    ushort_t (*hbt)[104], int tid)
{
  int row = tid >> 1, half = tid & 1;
  const float* xp = xrow_base + (size_t)row * 96 + half * 48;
  f32x4 v[12];
  float s = 0.f, sq = 0.f;
  #pragma unroll
  for (int i = 0; i < 12; i++) {
    v[i] = *reinterpret_cast<const f32x4*>(xp + i * 4);
    #pragma unroll
    for (int j = 0; j < 4; j++) { s += v[i][j]; sq += v[i][j] * v[i][j]; }
  }
  s  += __shfl_xor(s, 1);
  sq += __shfl_xor(sq, 1);
  float mean = s * (1.0f / 96.0f);
  float var  = sq * (1.0f / 96.0f) - mean * mean;
  float rstd = rsqrtf(var + 1e-5f);
  #pragma unroll
  for (int i8 = 0; i8 < 6; i8++) {
    short8 pk;
    #pragma unroll
    for (int j = 0; j < 8; j++) {
      int c = half * 48 + i8 * 8 + j;
      pk[j] = (short)f2bf((v[(i8 * 8 + j) >> 2][(i8 * 8 + j) & 3] - mean) * rstd * gg[c] + bb[c]);
    }
    *reinterpret_cast<short8*>(&hbt[row][half * 48 + i8 * 8]) = pk;
  }
}

// ---------------- fused LN1 + QKV projection ----------------
// block = 128 rows, 4 waves x (2 m-tiles). n processed in 3 groups of 6 tiles:
// bulk-load 18 B-frags, then 36 MFMAs (latency hidden by ILP).
__global__ __launch_bounds__(256, 2) void lnqkv_kernel(const float* __restrict__ x,
    const float* __restrict__ g, const float* __restrict__ b,
    const ushort_t* __restrict__ Wt, const float* __restrict__ biasq,
    ushort_t* __restrict__ qkv)
{
  __shared__ ushort_t hbt[128][104];
  int tid = threadIdx.x;
  size_t r0 = (size_t)blockIdx.x * 128;
  ln_to_lds(x + r0 * 96, g, b, hbt, tid);
  bar_lds();

  int w = tid >> 6, lane = tid & 63, g16 = lane >> 4, l15 = lane & 15;
  short8 af[2][3];
  #pragma unroll
  for (int mi = 0; mi < 2; mi++)
    #pragma unroll
    for (int ks = 0; ks < 3; ks++)
      af[mi][ks] = *reinterpret_cast<const short8*>(&hbt[w * 32 + mi * 16 + l15][ks * 32 + g16 * 8]);

  #pragma unroll
  for (int grp = 0; grp < 3; grp++) {
    short8 wf[18];
    #pragma unroll
    for (int j = 0; j < 6; j++)
      #pragma unroll
      for (int ks = 0; ks < 3; ks++)
        wf[j * 3 + ks] = *reinterpret_cast<const short8*>(
            &Wt[(size_t)((grp * 6 + j) * 16 + l15) * 96 + ks * 32 + g16 * 8]);
    f32x4 acc[2][6];
    #pragma unroll
    for (int mi = 0; mi < 2; mi++)
      #pragma unroll
      for (int j = 0; j < 6; j++) acc[mi][j] = (f32x4){0.f, 0.f, 0.f, 0.f};
    #pragma unroll
    for (int j = 0; j < 6; j++)
      #pragma unroll
      for (int ks = 0; ks < 3; ks++) {
        acc[0][j] = __builtin_amdgcn_mfma_f32_16x16x32_bf16(af[0][ks], wf[j * 3 + ks], acc[0][j], 0, 0, 0);
        acc[1][j] = __builtin_amdgcn_mfma_f32_16x16x32_bf16(af[1][ks], wf[j * 3 + ks], acc[1][j], 0, 0, 0);
      }
    #pragma unroll
    for (int j = 0; j < 6; j++) {
      int col = (grp * 6 + j) * 16 + l15;
      float bs = biasq[col];
      #pragma unroll
      for (int mi = 0; mi < 2; mi++)
        #pragma unroll
        for (int r = 0; r < 4; r++)
          qkv[(r0 + w * 32 + mi * 16 + g16 * 4 + r) * 288 + col] = f2bf(acc[mi][j][r] + bs);
    }
  }
}

// ---------------- fused window attention + output projection ----------------
__global__ __launch_bounds__(256) void attn2_kernel(
    const ushort_t* __restrict__ qkv, const ushort_t* __restrict__ Wot,
    const float* __restrict__ bo, const float* __restrict__ xres,
    float* __restrict__ x2)
{
  __shared__ ushort_t Pb[4][64][72];   // P[q][k'] per head
  __shared__ ushort_t Vt[4][32][72];   // V^T[d][k'] per head
  ushort_t (*O_lds)[104] = reinterpret_cast<ushort_t (*)[104]>(&Pb[0][0][0]); // aliases Pb

  int tid = threadIdx.x;
  int h = tid >> 6, lane = tid & 63, g = lane >> 4, l15 = lane & 15;
  int n = blockIdx.x;
  int wq_ = n & 15, hq = (n >> 4) & 15, rest = n >> 8;
  int dq = rest & 7, b = rest >> 3;
  int base = b * 131072 + dq * 16384 + hq * 256 + wq_ * 4;
  #define TOK(s) (base + ((s) >> 4) * 4096 + (((s) >> 2) & 3) * 64 + ((s) & 3))

  {
    int t = TOK(lane);
    const ushort_t* vp = qkv + (size_t)t * 288 + 192 + h * 24;
    short8 v0 = *(const short8*)(vp);
    short8 v1 = *(const short8*)(vp + 8);
    short8 v2 = *(const short8*)(vp + 16);
    #pragma unroll
    for (int d = 0; d < 8; d++) Vt[h][d][lane]      = (ushort_t)v0[d];
    #pragma unroll
    for (int d = 0; d < 8; d++) Vt[h][8 + d][lane]  = (ushort_t)v1[d];
    #pragma unroll
    for (int d = 0; d < 8; d++) Vt[h][16 + d][lane] = (ushort_t)v2[d];
  }

  short8 kf[4], qf[4];
  const short8 z8 = {0, 0, 0, 0, 0, 0, 0, 0};
  #pragma unroll
  for (int i = 0; i < 4; i++) {
    int t = TOK(i * 16 + l15);
    const ushort_t* rp = qkv + (size_t)t * 288 + h * 24 + g * 8;
    qf[i] = (g < 3) ? *(const short8*)(rp)      : z8;
    kf[i] = (g < 3) ? *(const short8*)(rp + 96) : z8;
  }

  f32x4 st[4][4];
  #pragma unroll
  for (int tm = 0; tm < 4; tm++)
    #pragma unroll
    for (int tn = 0; tn < 4; tn++)
      st[tm][tn] = __builtin_amdgcn_mfma_f32_16x16x32_bf16(kf[tm], qf[tn],
                    (f32x4){0.f, 0.f, 0.f, 0.f}, 0, 0, 0);

  const float scale = 0.20412414523193150818f;  // 1/sqrt(24)
  #pragma unroll
  for (int tn = 0; tn < 4; tn++) {
    float m = st[0][tn][0];
    #pragma unroll
    for (int tm = 0; tm < 4; tm++)
      #pragma unroll
      for (int r = 0; r < 4; r++) m = fmaxf(m, st[tm][tn][r]);
    m = fmaxf(m, __shfl_xor(m, 16));
    m = fmaxf(m, __shfl_xor(m, 32));
    float sum = 0.f;
    #pragma unroll
    for (int tm = 0; tm < 4; tm++)
      #pragma unroll
      for (int r = 0; r < 4; r++) {
        float e = __expf((st[tm][tn][r] - m) * scale);
        st[tm][tn][r] = e;
        sum += e;
      }
    sum += __shfl_xor(sum, 16);
    sum += __shfl_xor(sum, 32);
    float inv = 1.0f / sum;
    int q = tn * 16 + l15;
    #pragma unroll
    for (int tm = 0; tm < 4; tm++) {
      unsigned lo = (unsigned)f2bf(st[tm][tn][0] * inv) | ((unsigned)f2bf(st[tm][tn][1] * inv) << 16);
      unsigned hi = (unsigned)f2bf(st[tm][tn][2] * inv) | ((unsigned)f2bf(st[tm][tn][3] * inv) << 16);
      uint2 pk; pk.x = lo; pk.y = hi;
      *(uint2*)&Pb[h][q][tm * 16 + g * 4] = pk;
    }
  }

  f32x4 oacc[4][2];
  #pragma unroll
  for (int qt = 0; qt < 4; qt++)
    #pragma unroll
    for (int dt = 0; dt < 2; dt++) oacc[qt][dt] = (f32x4){0.f, 0.f, 0.f, 0.f};
  #pragma unroll
  for (int ks = 0; ks < 2; ks++) {
    short8 vb[2];
    #pragma unroll
    for (int dt = 0; dt < 2; dt++)
      vb[dt] = *(const short8*)&Vt[h][dt * 16 + l15][ks * 32 + g * 8];
    #pragma unroll
    for (int qt = 0; qt < 4; qt++) {
      short8 pa = *(const short8*)&Pb[h][qt * 16 + l15][ks * 32 + g * 8];
      #pragma unroll
      for (int dt = 0; dt < 2; dt++)
        oacc[qt][dt] = __builtin_amdgcn_mfma_f32_16x16x32_bf16(pa, vb[dt], oacc[qt][dt], 0, 0, 0);
    }
  }

  __syncthreads();
  #pragma unroll
  for (int qt = 0; qt < 4; qt++)
    #pragma unroll
    for (int dt = 0; dt < 2; dt++) {
      int d = dt * 16 + l15;
      if (d < 24) {
        #pragma unroll
        for (int r = 0; r < 4; r++)
          O_lds[qt * 16 + g * 4 + r][h * 24 + d] = f2bf(oacc[qt][dt][r]);
      }
    }
  __syncthreads();

  int w = h;
  f32x4 pacc[6];
  #pragma unroll
  for (int nt = 0; nt < 6; nt++) pacc[nt] = (f32x4){0.f, 0.f, 0.f, 0.f};
  #pragma unroll
  for (int ks = 0; ks < 3; ks++) {
    short8 pa = *(const short8*)&O_lds[w * 16 + l15][ks * 32 + g * 8];
    #pragma unroll
    for (int nt = 0; nt < 6; nt++) {
      short8 wb = *(const short8*)&Wot[(size_t)(nt * 16 + l15) * 96 + ks * 32 + g * 8];
      pacc[nt] = __builtin_amdgcn_mfma_f32_16x16x32_bf16(pa, wb, pacc[nt], 0, 0, 0);
    }
  }
  #pragma unroll
  for (int nt = 0; nt < 6; nt++) {
    int col = nt * 16 + l15;
    float bs = bo[col];
    #pragma unroll
    for (int r = 0; r < 4; r++) {
      int s = w * 16 + g * 4 + r;
      size_t t = (size_t)TOK(s);
      float v = pacc[nt][r] + bs + xres[t * 96 + col];
      x2[t * 96 + col] = v;
    }
  }
  #undef TOK
}

// ---------------- fused LN2 + MLP + residual ----------------
// block = 128 rows, 4 waves x (2 m-tiles). mid chunked 4 x 96 cols through LDS.
// Bulk-load 18 weight frags per phase; W2 loads issued before the barrier so
// they stay in flight (bar_lds does not drain vmcnt).
__global__ __launch_bounds__(256, 2) void mlp2_kernel(
    const float* __restrict__ x2, const float* __restrict__ g, const float* __restrict__ b,
    const ushort_t* __restrict__ W1t, const float* __restrict__ b1,
    const ushort_t* __restrict__ W2t, const float* __restrict__ b2,
    float* __restrict__ out)
{
  __shared__ ushort_t hbt[128][104];
  __shared__ ushort_t mid[128][104];
  int tid = threadIdx.x;
  size_t r0 = (size_t)blockIdx.x * 128;
  ln_to_lds(x2 + r0 * 96, g, b, hbt, tid);
  bar_lds();

  int w = tid >> 6, lane = tid & 63, g16 = lane >> 4, l15 = lane & 15;
  short8 af[2][3];
  #pragma unroll
  for (int mi = 0; mi < 2; mi++)
    #pragma unroll
    for (int ks = 0; ks < 3; ks++)
      af[mi][ks] = *reinterpret_cast<const short8*>(&hbt[w * 32 + mi * 16 + l15][ks * 32 + g16 * 8]);

  f32x4 oacc[2][6];
  #pragma unroll
  for (int mi = 0; mi < 2; mi++)
    #pragma unroll
    for (int nt = 0; nt < 6; nt++) oacc[mi][nt] = (f32x4){0.f, 0.f, 0.f, 0.f};

  #pragma unroll
  for (int cc = 0; cc < 4; cc++) {
    // ---- bulk-load W1 chunk frags ----
    short8 w1f[18];
    #pragma unroll
    for (int j = 0; j < 6; j++)
      #pragma unroll
      for (int ks = 0; ks < 3; ks++)
        w1f[j * 3 + ks] = *reinterpret_cast<const short8*>(
            &W1t[(size_t)(cc * 96 + j * 16 + l15) * 96 + ks * 32 + g16 * 8]);
    // ---- phase 1 MFMAs ----
    f32x4 acc[2][6];
    #pragma unroll
    for (int mi = 0; mi < 2; mi++)
      #pragma unroll
      for (int j = 0; j < 6; j++) acc[mi][j] = (f32x4){0.f, 0.f, 0.f, 0.f};
    #pragma unroll
    for (int j = 0; j < 6; j++)
      #pragma unroll
      for (int ks = 0; ks < 3; ks++) {
        acc[0][j] = __builtin_amdgcn_mfma_f32_16x16x32_bf16(af[0][ks], w1f[j * 3 + ks], acc[0][j], 0, 0, 0);
        acc[1][j] = __builtin_amdgcn_mfma_f32_16x16x32_bf16(af[1][ks], w1f[j * 3 + ks], acc[1][j], 0, 0, 0);
      }
    // ---- issue W2 chunk loads now (fly across gelu + barrier) ----
    short8 w2f[18];
    #pragma unroll
    for (int j = 0; j < 6; j++)
      #pragma unroll
      for (int ks = 0; ks < 3; ks++)
        w2f[j * 3 + ks] = *reinterpret_cast<const short8*>(
            &W2t[(size_t)(j * 16 + l15) * 384 + cc * 96 + ks * 32 + g16 * 8]);
    // ---- gelu + pack to mid ----
    #pragma unroll
    for (int j = 0; j < 6; j++) {
      int colg = cc * 96 + j * 16 + l15;
      float bs = b1[colg];
      #pragma unroll
      for (int mi = 0; mi < 2; mi++)
        #pragma unroll
        for (int r = 0; r < 4; r++)
          mid[w * 32 + mi * 16 + g16 * 4 + r][j * 16 + l15] = f2bf(gelu_exact(acc[mi][j][r] + bs));
    }
    bar_lds();
    // ---- read mid frags ----
    short8 a2[2][3];
    #pragma unroll
    for (int mi = 0; mi < 2; mi++)
      #pragma unroll
      for (int ks = 0; ks < 3; ks++)
        a2[mi][ks] = *reinterpret_cast<const short8*>(&mid[w * 32 + mi * 16 + l15][ks * 32 + g16 * 8]);
    bar_lds();   // a2 retired to regs; next chunk may overwrite mid
    // ---- phase 2 MFMAs ----
    #pragma unroll
    for (int j = 0; j < 6; j++)
      #pragma unroll
      for (int ks = 0; ks < 3; ks++) {
        oacc[0][j] = __builtin_amdgcn_mfma_f32_16x16x32_bf16(a2[0][ks], w2f[j * 3 + ks], oacc[0][j], 0, 0, 0);
        oacc[1][j] = __builtin_amdgcn_mfma_f32_16x16x32_bf16(a2[1][ks], w2f[j * 3 + ks], oacc[1][j], 0, 0, 0);
      }
  }

  // epilogue: out = oacc + b2 + residual(x2)
  #pragma unroll
  for (int j = 0; j < 6; j++) {
    int col = j * 16 + l15;
    float bs = b2[col];
    #pragma unroll
    for (int mi = 0; mi < 2; mi++)
      #pragma unroll
      for (int r = 0; r < 4; r++) {
        size_t row = r0 + w * 32 + mi * 16 + g16 * 4 + r;
        out[row * 96 + col] = oacc[mi][j][r] + bs + x2[row * 96 + col];
      }
  }
}

// ---------------- launch ----------------
extern "C" void kernel_launch(void* const* d_in, const int* in_sizes, int n_in,
                              void* d_out, int out_size, void* d_ws, size_t ws_size,
                              hipStream_t stream)
{
  (void)in_sizes; (void)n_in; (void)out_size; (void)ws_size;
  const float* x    = (const float*)d_in[0];
  const float* ln1g = (const float*)d_in[1];
  const float* ln1b = (const float*)d_in[2];
  const float* wq   = (const float*)d_in[3];
  const float* bq   = (const float*)d_in[4];
  const float* wk   = (const float*)d_in[5];
  const float* bk   = (const float*)d_in[6];
  const float* wv   = (const float*)d_in[7];
  const float* bv   = (const float*)d_in[8];
  const float* wo   = (const float*)d_in[9];
  const float* bo   = (const float*)d_in[10];
  const float* ln2g = (const float*)d_in[11];
  const float* ln2b = (const float*)d_in[12];
  const float* w1   = (const float*)d_in[13];
  const float* b1   = (const float*)d_in[14];
  const float* w2   = (const float*)d_in[15];
  const float* b2   = (const float*)d_in[16];

  char* ws = (char*)d_ws;
  ushort_t* qkv  = (ushort_t*)(ws);                          // [N,288] bf16  150,994,944 B
  char* wsw      = ws + 150994944;
  ushort_t* Wqkv = (ushort_t*)(wsw);                         // [288][96]
  ushort_t* Wo   = (ushort_t*)(wsw + 55296);                 // [96][96]
  ushort_t* W1   = (ushort_t*)(wsw + 55296 + 18432);         // [384][96]
  ushort_t* W2   = (ushort_t*)(wsw + 55296 + 18432 + 73728); // [96][384]
  float*    biasq= (float*)   (wsw + 55296 + 18432 + 73728 + 73728); // [288] fp32
  float* x2 = (float*)d_out;   // post-attention residual lives in d_out

  prep_kernel<<<434, 256, 0, stream>>>(wq, wk, wv, wo, w1, w2, bq, bk, bv,
                                       Wqkv, Wo, W1, W2, biasq);
  lnqkv_kernel<<<NTOK / 128, 256, 0, stream>>>(x, ln1g, ln1b, Wqkv, biasq, qkv);
  attn2_kernel<<<4096, 256, 0, stream>>>(qkv, Wo, bo, x, x2);
  mlp2_kernel<<<NTOK / 128, 256, 0, stream>>>(x2, ln2g, ln2b, W1, b1, W2, b2, (float*)d_out);
}